// Round 9
// baseline (3581.040 us; speedup 1.0000x reference)
//
#include <hip/hip_runtime.h>
#include <hip/hip_bf16.h>

// GRU: SEQ=512, B=64, I=512, H=1024, O=512
#define SEQL 512
#define BATCH 64
#define INF 512
#define HID 1024
#define OUTF 512
#define SB (SEQL*BATCH)
#define BH (BATCH*HID)

typedef __attribute__((ext_vector_type(8))) __bf16 bf16x8;
typedef __attribute__((ext_vector_type(4))) float f32x4;

__device__ inline bf16x8 ld_bf8(const void* p) { return *reinterpret_cast<const bf16x8*>(p); }
__device__ inline unsigned short f2bf(float f) { __bf16 b = (__bf16)f; return __builtin_bit_cast(unsigned short, b); }

// Coherent 8B store: relaxed agent-scope atomic -> write-through to IF, no cache maintenance.
__device__ inline void st_u64c(void* p, unsigned long long v) {
    __hip_atomic_store((unsigned long long*)p, v, __ATOMIC_RELAXED, __HIP_MEMORY_SCOPE_AGENT);
}

// ---------------- prep kernels ----------------
__global__ void cvt_f32_bf16(const float* __restrict__ src, unsigned short* __restrict__ dst, int n) {
    int i = (blockIdx.x * blockDim.x + threadIdx.x) * 4;
    if (i < n) {
        float4 v = *reinterpret_cast<const float4*>(src + i);
        ushort4 o = make_ushort4(f2bf(v.x), f2bf(v.y), f2bf(v.z), f2bf(v.w));
        *reinterpret_cast<ushort4*>(dst + i) = o;
    }
}

__global__ void make_bias2(const float* bxz, const float* bhz, const float* bxr,
                           const float* bhr, float* bias2) {
    int i = blockIdx.x * blockDim.x + threadIdx.x;
    if (i < HID) bias2[i] = bxz[i] + bhz[i];
    else if (i < 2*HID) bias2[i] = bxr[i-HID] + bhr[i-HID];
}

__global__ void fail_sentinel(float* o) { o[0] = 1e9f; }

// ---------------- tiled NT GEMM (unchanged, validated) ----------------
__global__ __launch_bounds__(256, 2) void gemm_nt_f32(
        const unsigned short* __restrict__ A, int lda,
        const unsigned short* __restrict__ Bw, int ldb,
        const float* __restrict__ bias,
        float* __restrict__ Cf, int N, int K) {
    __shared__ __align__(16) char lds[32768];
    const int tid = threadIdx.x;
    const int ntn = N >> 7;
    const int bm = blockIdx.x / ntn, bn = blockIdx.x % ntn;
    const int rowbase = bm << 7, colbase = bn << 7;
    const int wave = tid >> 6, lane = tid & 63, lo = lane & 15, hi = lane >> 4;
    const int vm = wave >> 1, vn = wave & 1;

    auto stage = [&](int abase, int k0) {
        #pragma unroll
        for (int i = 0; i < 2; i++) {
            int linear = i * 256 + tid;
            int r = linear >> 2, s = linear & 3;
            int c = (s - (r >> 1)) & 3;
            const unsigned short* ga = A + (size_t)(rowbase + r) * lda + k0 + c * 8;
            const unsigned short* gb = Bw + (size_t)(colbase + r) * ldb + k0 + c * 8;
            __builtin_amdgcn_global_load_lds(
                (const __attribute__((address_space(1))) unsigned int*)ga,
                (__attribute__((address_space(3))) unsigned int*)(lds + abase + linear * 16), 16, 0, 0);
            __builtin_amdgcn_global_load_lds(
                (const __attribute__((address_space(1))) unsigned int*)gb,
                (__attribute__((address_space(3))) unsigned int*)(lds + 16384 + abase + linear * 16), 16, 0, 0);
        }
    };

    f32x4 acc[4][4] = {};
    const int nk = K >> 5;
    stage(0, 0);
    for (int kt = 0; kt < nk; kt++) {
        __syncthreads();
        if (kt + 1 < nk) stage(((kt + 1) & 1) * 8192, (kt + 1) << 5);
        const char* cA = lds + (kt & 1) * 8192;
        const char* cB = lds + 16384 + (kt & 1) * 8192;
        bf16x8 af[4], bfr[4];
        #pragma unroll
        for (int m = 0; m < 4; m++) {
            int r = vm * 64 + m * 16 + lo;
            af[m] = ld_bf8(cA + r * 64 + 16 * ((hi + (r >> 1)) & 3));
        }
        #pragma unroll
        for (int n = 0; n < 4; n++) {
            int r = vn * 64 + n * 16 + lo;
            bfr[n] = ld_bf8(cB + r * 64 + 16 * ((hi + (r >> 1)) & 3));
        }
        #pragma unroll
        for (int m = 0; m < 4; m++)
            #pragma unroll
            for (int n = 0; n < 4; n++)
                acc[m][n] = __builtin_amdgcn_mfma_f32_16x16x32_bf16(af[m], bfr[n], acc[m][n], 0, 0, 0);
        __syncthreads();
    }

    #pragma unroll
    for (int n = 0; n < 4; n++) {
        int col = colbase + vn * 64 + n * 16 + lo;
        float bv = bias[col];
        #pragma unroll
        for (int m = 0; m < 4; m++)
            #pragma unroll
            for (int r = 0; r < 4; r++) {
                int row = rowbase + vm * 64 + m * 16 + hi * 4 + r;
                Cf[(size_t)row * N + col] = acc[m][n][r] + bv;
            }
    }
}

// ---------------- persistent GRU scan v5: XOR-swizzled h tile (coalesced stage) ----------------
// 256 WGs x 192 threads; rb = wid>>6 in 0..3 (16 batch rows, 4 independent scan groups),
// cb = wid&63 (16 h-cols); wave g = gate {z,r,hcand}.
// LDS: [0,96K) wh; [96K,128K) h tile; [128K,131K) Px; [131K,131.5K) T repack.
// h tile (round-8 post-mortem: fragment-major order made every 16B stage load its own IF
// transaction -- 524K tiny transactions/step): unit u now holds global chunk
//   (row = u>>7, slot = (u&127) ^ (row&7))      [XOR swizzle, G21: swizzle lives in the
// SOURCE address, LDS dest stays linear for global_load_lds]
//   stage:  consecutive lanes -> same row, contiguous slot runs of 8 -> 128B transactions (8x fewer)
//   consume: lane reads byte lo*2048 + (((kb<<2)|hi)^(lo&7))*16 -> bank bits uniform-8 (0-conflict,
//            same class as the wh reads measured conflict-free in r5/r6)
// Sync unchanged (validated r8): wave0 repack -> one 8B coherent store/lane -> vmcnt(0) ->
// per-WG flag store (no RMW); consumers x-prefetch then ballot-poll 64 flags.
__global__ __launch_bounds__(192, 1) void gru_scan(
        const unsigned short* __restrict__ Whc,   // [3][H][H]
        const unsigned short* __restrict__ Wxc,   // [3][H][I]
        const unsigned short* __restrict__ xbf,   // [S*B][I]
        unsigned short* __restrict__ hs,          // [S+1][B][H]
        const float* __restrict__ bias2,          // [2H]
        const float* __restrict__ bxh,
        const float* __restrict__ bhh,
        unsigned int* flags) {                    // [4][64] per-WG step flags
    __shared__ __align__(16) char lds[134656];
    const int tid = threadIdx.x;
    const int wid = blockIdx.x;
    const int rb = wid >> 6;          // 0..3
    const int cb = wid & 63;
    const int g = tid / 64;
    const int lane = tid & 63, lo = lane & 15, hi = lane >> 4;
    const int col = cb * 16 + lo;
    char* whl = lds + g * 32768;                       // this wave's 32 wh frags
    char* hstage = lds + 98304;                        // 32 KB swizzled h tile
    f32x4* Px = (f32x4*)(lds + 131072);                // 3 KB exchange
    unsigned short* T = (unsigned short*)(lds + 134144); // 512 B store-repack

    // ---- stage wh slices into LDS (once) ----
    {
        const unsigned short* ph = Whc + ((size_t)g * HID + col) * HID + hi * 8;
        #pragma unroll
        for (int kb = 0; kb < 32; kb++)
            __builtin_amdgcn_global_load_lds(
                (const __attribute__((address_space(1))) unsigned int*)(ph + kb * 32),
                (__attribute__((address_space(3))) unsigned int*)(whl + kb * 1024 + lane * 16), 16, 0, 0);
    }
    __syncthreads();

    const float bzv  = bias2[col];
    const float brv  = bias2[HID + col];
    const float bxhv = bxh[col];
    const float bhhv = bhh[col];
    float hst[4] = {0.f, 0.f, 0.f, 0.f};   // fp32 state: row = rb*16 + hi*4 + r, col
    const unsigned short* wxp = Wxc + ((size_t)g * HID + col) * INF + hi * 8;
    const int x7 = lo & 7;                  // consume-side XOR key

    // wx fragments hoisted (step-invariant; if the compiler sinks them the loads are L2-warm)
    bf16x8 wxf[16];
    #pragma unroll
    for (int kb = 0; kb < 16; kb++) wxf[kb] = ld_bf8(wxp + kb * 32);

    // x-side preacts for t=0
    f32x4 ax = {0,0,0,0};
    {
        const unsigned short* xp = xbf + ((size_t)(rb * 16 + lo)) * INF + hi * 8;
        #pragma unroll
        for (int kb = 0; kb < 16; kb++)
            ax = __builtin_amdgcn_mfma_f32_16x16x32_bf16(ld_bf8(xp + kb * 32), wxf[kb], ax, 0, 0, 0);
    }

    for (int t = 0; t < SEQL; t++) {
        // --- issue next-step x loads early (cold HBM; land under stage+consume) ---
        bf16x8 xv[16];
        if (t + 1 < SEQL) {
            const unsigned short* xp = xbf + ((size_t)(t + 1) * BATCH + rb * 16 + lo) * INF + hi * 8;
            #pragma unroll
            for (int kb = 0; kb < 16; kb++) xv[kb] = ld_bf8(xp + kb * 32);
        }

        // --- stage h[t] tile: XOR-swizzled source, linear LDS dest ---
        if (t > 0) {
            const unsigned short* hsrc = hs + (size_t)t * BH + (size_t)(rb * 16) * HID;
            #pragma unroll
            for (int it = 0; it < 10; it++) {
                int u = it * 192 + tid;
                int row = u >> 7, sg = (u & 127) ^ (row & 7);
                __builtin_amdgcn_global_load_lds(
                    (const __attribute__((address_space(1))) unsigned int*)(hsrc + (size_t)row * HID + sg * 8),
                    (__attribute__((address_space(3))) unsigned int*)(hstage + u * 16), 16, 0, 17 /*SC0|SC1*/);
            }
            if (tid < 128) {
                int u = 1920 + tid;
                int row = u >> 7, sg = (u & 127) ^ (row & 7);
                __builtin_amdgcn_global_load_lds(
                    (const __attribute__((address_space(1))) unsigned int*)(hsrc + (size_t)row * HID + sg * 8),
                    (__attribute__((address_space(3))) unsigned int*)(hstage + u * 16), 16, 0, 17);
            }
        }
        __syncthreads();   // stage landed

        // --- h-side preacts: swizzled, conflict-free LDS reads ---
        f32x4 ah = {0,0,0,0};
        if (t > 0) {
            #pragma unroll
            for (int kb = 0; kb < 32; kb++) {
                bf16x8 w = ld_bf8(whl + kb * 1024 + lane * 16);
                bf16x8 a = ld_bf8(hstage + ((lo * 128 + (((kb << 2) | hi) ^ x7)) << 4));
                ah = __builtin_amdgcn_mfma_f32_16x16x32_bf16(a, w, ah, 0, 0, 0);
            }
        }

        // --- exchange r-pre and both hcand parts via LDS ---
        if (g == 1) {
            f32x4 v;
            #pragma unroll
            for (int r = 0; r < 4; r++) v[r] = ah[r] + ax[r] + brv;
            Px[0 * 64 + lane] = v;
        } else if (g == 2) {
            f32x4 v, w;
            #pragma unroll
            for (int r = 0; r < 4; r++) { v[r] = ah[r] + bhhv; w[r] = ax[r] + bxhv; }
            Px[1 * 64 + lane] = v;
            Px[2 * 64 + lane] = w;
        }
        __syncthreads();

        // --- finalize by wave 0: gates -> new h -> T-repack -> ONE 8B coherent store/lane ---
        if (g == 0) {
            unsigned short* hdst = hs + (size_t)(t + 1) * BH;
            f32x4 pr = Px[0 * 64 + lane];
            f32x4 ph_ = Px[1 * 64 + lane];
            f32x4 px_ = Px[2 * 64 + lane];
            #pragma unroll
            for (int r = 0; r < 4; r++) {
                float z  = 1.f / (1.f + __expf(-(ah[r] + ax[r] + bzv)));
                float rr = 1.f / (1.f + __expf(-pr[r]));
                float hc = tanhf(px_[r] + rr * ph_[r]);
                hst[r] = (1.f - z) * hst[r] + z * hc;
                T[(hi * 4 + r) * 16 + lo] = f2bf(hst[r]);   // T[row16][col16]
            }
            asm volatile("s_waitcnt lgkmcnt(0)" ::: "memory");  // cross-lane T writes complete
            int row = lane >> 2, q = lane & 3;
            unsigned long long val = *(const unsigned long long*)(T + row * 16 + q * 4);
            st_u64c(hdst + (size_t)(rb * 16 + row) * HID + cb * 16 + q * 4, val);
            asm volatile("s_waitcnt vmcnt(0)" ::: "memory");    // h-store at the IF
        }
        if (tid == 0)
            __hip_atomic_store(flags + rb * 64 + cb, (unsigned int)(t + 1),
                               __ATOMIC_RELAXED, __HIP_MEMORY_SCOPE_AGENT);

        // --- x-MFMAs for t+1 (loads issued at step top) overlap flag propagation; then poll ---
        f32x4 nax = {0,0,0,0};
        if (t + 1 < SEQL) {
            #pragma unroll
            for (int kb = 0; kb < 16; kb++)
                nax = __builtin_amdgcn_mfma_f32_16x16x32_bf16(xv[kb], wxf[kb], nax, 0, 0, 0);
            const unsigned int* fl = flags + rb * 64 + lane;
            unsigned int tgt = (unsigned int)(t + 1);
            while (!__all(__hip_atomic_load(fl, __ATOMIC_RELAXED, __HIP_MEMORY_SCOPE_AGENT) >= tgt))
                __builtin_amdgcn_s_sleep(1);
        }
        ax = nax;
    }
}

// ---------------- host ----------------
extern "C" void kernel_launch(void* const* d_in, const int* in_sizes, int n_in,
                              void* d_out, int out_size, void* d_ws, size_t ws_size,
                              hipStream_t stream) {
    const float* x   = (const float*)d_in[0];
    const float* Wxz = (const float*)d_in[1];
    const float* bxz = (const float*)d_in[2];
    const float* Whz = (const float*)d_in[3];
    const float* bhz = (const float*)d_in[4];
    const float* Wxr = (const float*)d_in[5];
    const float* bxr = (const float*)d_in[6];
    const float* Whr = (const float*)d_in[7];
    const float* bhr = (const float*)d_in[8];
    const float* Wxh = (const float*)d_in[9];
    const float* bxh = (const float*)d_in[10];
    const float* Whh = (const float*)d_in[11];
    const float* bhh = (const float*)d_in[12];
    const float* Why = (const float*)d_in[13];
    const float* bhy = (const float*)d_in[14];

    char* ws = (char*)d_ws;
    size_t off = 0;
    auto alloc = [&](size_t bytes) { char* p = ws + off; off += (bytes + 255) & ~(size_t)255; return p; };
    unsigned short* Whc   = (unsigned short*)alloc((size_t)3 * HID * HID * 2);
    unsigned short* Wxc   = (unsigned short*)alloc((size_t)3 * HID * INF * 2);
    unsigned short* Whyb  = (unsigned short*)alloc((size_t)OUTF * HID * 2);
    float*          bias2 = (float*)alloc((size_t)2 * HID * 4);
    unsigned short* hsbuf = (unsigned short*)alloc((size_t)(SEQL + 1) * BATCH * HID * 2);
    unsigned int*   flags = (unsigned int*)alloc(1024);
    unsigned short* x_bf  = (unsigned short*)d_out;  // dead until the final GEMM

    if (off > ws_size) {
        fail_sentinel<<<dim3(1), dim3(1), 0, stream>>>((float*)d_out);
        return;
    }

    auto cvt = [&](const float* s, unsigned short* d, size_t n) {
        cvt_f32_bf16<<<dim3((unsigned)((n / 4 + 255) / 256)), dim3(256), 0, stream>>>(s, d, (int)n);
    };
    cvt(x, x_bf, (size_t)SB * INF);
    cvt(Whz, Whc, (size_t)HID * HID);
    cvt(Whr, Whc + (size_t)HID * HID, (size_t)HID * HID);
    cvt(Whh, Whc + (size_t)2 * HID * HID, (size_t)HID * HID);
    cvt(Wxz, Wxc, (size_t)HID * INF);
    cvt(Wxr, Wxc + (size_t)HID * INF, (size_t)HID * INF);
    cvt(Wxh, Wxc + (size_t)2 * HID * INF, (size_t)HID * INF);
    cvt(Why, Whyb, (size_t)OUTF * HID);
    make_bias2<<<dim3(8), dim3(256), 0, stream>>>(bxz, bhz, bxr, bhr, bias2);
    (void)hipMemsetAsync(flags, 0, 1024, stream);   // reset per launch (graph-replay safe)

    gru_scan<<<dim3(256), dim3(192), 0, stream>>>(Whc, Wxc, x_bf, hsbuf, bias2, bxh, bhh, flags);

    gemm_nt_f32<<<dim3((SB / 128) * (OUTF / 128)), dim3(256), 0, stream>>>(
        hsbuf + (size_t)BATCH * HID, HID, Whyb, HID, bhy, (float*)d_out, OUTF, HID);
}

// Round 10
// 3111.489 us; speedup vs baseline: 1.1509x; 1.1509x over previous
//
#include <hip/hip_runtime.h>
#include <hip/hip_bf16.h>

// GRU: SEQ=512, B=64, I=512, H=1024, O=512
#define SEQL 512
#define BATCH 64
#define INF 512
#define HID 1024
#define OUTF 512
#define SB (SEQL*BATCH)
#define BH (BATCH*HID)

typedef __attribute__((ext_vector_type(8))) __bf16 bf16x8;
typedef __attribute__((ext_vector_type(4))) float f32x4;

__device__ inline bf16x8 ld_bf8(const void* p) { return *reinterpret_cast<const bf16x8*>(p); }
__device__ inline unsigned short f2bf(float f) { __bf16 b = (__bf16)f; return __builtin_bit_cast(unsigned short, b); }

// Coherent 8B store: relaxed agent-scope atomic -> write-through to IF, no cache maintenance.
__device__ inline void st_u64c(void* p, unsigned long long v) {
    __hip_atomic_store((unsigned long long*)p, v, __ATOMIC_RELAXED, __HIP_MEMORY_SCOPE_AGENT);
}

// ---------------- prep kernels ----------------
__global__ void cvt_f32_bf16(const float* __restrict__ src, unsigned short* __restrict__ dst, int n) {
    int i = (blockIdx.x * blockDim.x + threadIdx.x) * 4;
    if (i < n) {
        float4 v = *reinterpret_cast<const float4*>(src + i);
        ushort4 o = make_ushort4(f2bf(v.x), f2bf(v.y), f2bf(v.z), f2bf(v.w));
        *reinterpret_cast<ushort4*>(dst + i) = o;
    }
}

__global__ void make_bias2(const float* bxz, const float* bhz, const float* bxr,
                           const float* bhr, float* bias2) {
    int i = blockIdx.x * blockDim.x + threadIdx.x;
    if (i < HID) bias2[i] = bxz[i] + bhz[i];
    else if (i < 2*HID) bias2[i] = bxr[i-HID] + bhr[i-HID];
}

__global__ void fail_sentinel(float* o) { o[0] = 1e9f; }

// ---------------- tiled NT GEMM (unchanged, validated) ----------------
__global__ __launch_bounds__(256, 2) void gemm_nt_f32(
        const unsigned short* __restrict__ A, int lda,
        const unsigned short* __restrict__ Bw, int ldb,
        const float* __restrict__ bias,
        float* __restrict__ Cf, int N, int K) {
    __shared__ __align__(16) char lds[32768];
    const int tid = threadIdx.x;
    const int ntn = N >> 7;
    const int bm = blockIdx.x / ntn, bn = blockIdx.x % ntn;
    const int rowbase = bm << 7, colbase = bn << 7;
    const int wave = tid >> 6, lane = tid & 63, lo = lane & 15, hi = lane >> 4;
    const int vm = wave >> 1, vn = wave & 1;

    auto stage = [&](int abase, int k0) {
        #pragma unroll
        for (int i = 0; i < 2; i++) {
            int linear = i * 256 + tid;
            int r = linear >> 2, s = linear & 3;
            int c = (s - (r >> 1)) & 3;
            const unsigned short* ga = A + (size_t)(rowbase + r) * lda + k0 + c * 8;
            const unsigned short* gb = Bw + (size_t)(colbase + r) * ldb + k0 + c * 8;
            __builtin_amdgcn_global_load_lds(
                (const __attribute__((address_space(1))) unsigned int*)ga,
                (__attribute__((address_space(3))) unsigned int*)(lds + abase + linear * 16), 16, 0, 0);
            __builtin_amdgcn_global_load_lds(
                (const __attribute__((address_space(1))) unsigned int*)gb,
                (__attribute__((address_space(3))) unsigned int*)(lds + 16384 + abase + linear * 16), 16, 0, 0);
        }
    };

    f32x4 acc[4][4] = {};
    const int nk = K >> 5;
    stage(0, 0);
    for (int kt = 0; kt < nk; kt++) {
        __syncthreads();
        if (kt + 1 < nk) stage(((kt + 1) & 1) * 8192, (kt + 1) << 5);
        const char* cA = lds + (kt & 1) * 8192;
        const char* cB = lds + 16384 + (kt & 1) * 8192;
        bf16x8 af[4], bfr[4];
        #pragma unroll
        for (int m = 0; m < 4; m++) {
            int r = vm * 64 + m * 16 + lo;
            af[m] = ld_bf8(cA + r * 64 + 16 * ((hi + (r >> 1)) & 3));
        }
        #pragma unroll
        for (int n = 0; n < 4; n++) {
            int r = vn * 64 + n * 16 + lo;
            bfr[n] = ld_bf8(cB + r * 64 + 16 * ((hi + (r >> 1)) & 3));
        }
        #pragma unroll
        for (int m = 0; m < 4; m++)
            #pragma unroll
            for (int n = 0; n < 4; n++)
                acc[m][n] = __builtin_amdgcn_mfma_f32_16x16x32_bf16(af[m], bfr[n], acc[m][n], 0, 0, 0);
        __syncthreads();
    }

    #pragma unroll
    for (int n = 0; n < 4; n++) {
        int col = colbase + vn * 64 + n * 16 + lo;
        float bv = bias[col];
        #pragma unroll
        for (int m = 0; m < 4; m++)
            #pragma unroll
            for (int r = 0; r < 4; r++) {
                int row = rowbase + vm * 64 + m * 16 + hi * 4 + r;
                Cf[(size_t)row * N + col] = acc[m][n][r] + bv;
            }
    }
}

// ---------------- persistent GRU scan v6: r8 layout + split-half flag pipeline ----------------
// 256 WGs x 192 threads; rb = wid>>6 in 0..3 (16 batch rows, 4 independent scan groups),
// cb = wid&63 (16 h-cols); wave g = gate {z,r,hcand}.
// LDS: [0,96K) wh; [96K,128K) h tile; [128K,131K) Px; [131K,131.5K) T repack.
// h tile is FRAGMENT-MAJOR (r8, measured ~0 bank conflicts; r9 ERRATum: XOR-quad scatter
// measured ~4-way-conflicted despite uniform bank coverage -- only consecutive-lane ->
// consecutive-16B LDS patterns are reliably conflict-free): unit v = kb*64+lane holds global
// chunk (row = v&15, slot = v>>4); consume read = hstage + kb*1024 + lane*16.
// NEW (split-half pipeline): chunk (row, slot) depends only on producer cb = slot>>1, so:
//   end of iter:  poll flags[0..31]  (half A, slots 0..63 = k 0..511)
//   top of iter:  issue stage-A  ->  poll flags[32..63] (B straggler wait overlaps A in
//                 flight; the poll's implicit vmcnt drain completes A during the poll RTT)
//                 -> issue stage-B -> one barrier -> consume 32 kb.
// Sync (validated r8): wave0 repack -> one 8B coherent store/lane -> vmcnt(0) -> flag store
// (no RMW); x-prefetch+MFMA sit between flag store and poll-A.
__global__ __launch_bounds__(192, 1) void gru_scan(
        const unsigned short* __restrict__ Whc,   // [3][H][H]
        const unsigned short* __restrict__ Wxc,   // [3][H][I]
        const unsigned short* __restrict__ xbf,   // [S*B][I]
        unsigned short* __restrict__ hs,          // [S+1][B][H]
        const float* __restrict__ bias2,          // [2H]
        const float* __restrict__ bxh,
        const float* __restrict__ bhh,
        unsigned int* flags) {                    // [4][64] per-WG step flags
    __shared__ __align__(16) char lds[134656];
    const int tid = threadIdx.x;
    const int wid = blockIdx.x;
    const int rb = wid >> 6;          // 0..3
    const int cb = wid & 63;
    const int g = tid / 64;
    const int lane = tid & 63, lo = lane & 15, hi = lane >> 4;
    const int col = cb * 16 + lo;
    char* whl = lds + g * 32768;                       // this wave's 32 wh frags
    char* hstage = lds + 98304;                        // 32 KB fragment-major h tile
    f32x4* Px = (f32x4*)(lds + 131072);                // 3 KB exchange
    unsigned short* T = (unsigned short*)(lds + 134144); // 512 B store-repack

    // ---- stage wh slices into LDS (once) ----
    {
        const unsigned short* ph = Whc + ((size_t)g * HID + col) * HID + hi * 8;
        #pragma unroll
        for (int kb = 0; kb < 32; kb++)
            __builtin_amdgcn_global_load_lds(
                (const __attribute__((address_space(1))) unsigned int*)(ph + kb * 32),
                (__attribute__((address_space(3))) unsigned int*)(whl + kb * 1024 + lane * 16), 16, 0, 0);
    }
    __syncthreads();

    const float bzv  = bias2[col];
    const float brv  = bias2[HID + col];
    const float bxhv = bxh[col];
    const float bhhv = bhh[col];
    float hst[4] = {0.f, 0.f, 0.f, 0.f};   // fp32 state: row = rb*16 + hi*4 + r, col
    const unsigned short* wxp = Wxc + ((size_t)g * HID + col) * INF + hi * 8;
    const unsigned int* flA = flags + rb * 64 + (lane & 31);        // half-A producers
    const unsigned int* flB = flags + rb * 64 + 32 + (lane & 31);   // half-B producers

    // x-side preacts for t=0
    f32x4 ax = {0,0,0,0};
    {
        const unsigned short* xp = xbf + ((size_t)(rb * 16 + lo)) * INF + hi * 8;
        #pragma unroll
        for (int kb = 0; kb < 16; kb++)
            ax = __builtin_amdgcn_mfma_f32_16x16x32_bf16(ld_bf8(xp + kb * 32), ld_bf8(wxp + kb * 32), ax, 0, 0, 0);
    }

    for (int t = 0; t < SEQL; t++) {
        // --- stage h[t]: half A (poll-A happened at end of previous iteration) ---
        if (t > 0) {
            const unsigned short* hsrc = hs + (size_t)t * BH + (size_t)(rb * 16) * HID;
            #pragma unroll
            for (int it = 0; it < 6; it++) {
                int v = it * 192 + tid;
                if (v < 1024)
                    __builtin_amdgcn_global_load_lds(
                        (const __attribute__((address_space(1))) unsigned int*)(hsrc + (size_t)(v & 15) * HID + (v >> 4) * 8),
                        (__attribute__((address_space(3))) unsigned int*)(hstage + v * 16), 16, 0, 17 /*SC0|SC1*/);
            }
            // --- poll half-B producers; A-loads complete under this RTT ---
            {
                unsigned int tgt = (unsigned int)t;
                while (!__all(__hip_atomic_load(flB, __ATOMIC_RELAXED, __HIP_MEMORY_SCOPE_AGENT) >= tgt))
                    __builtin_amdgcn_s_sleep(1);
            }
            // --- stage half B ---
            #pragma unroll
            for (int it = 0; it < 6; it++) {
                int v = 1024 + it * 192 + tid;
                if (v < 2048)
                    __builtin_amdgcn_global_load_lds(
                        (const __attribute__((address_space(1))) unsigned int*)(hsrc + (size_t)(v & 15) * HID + (v >> 4) * 8),
                        (__attribute__((address_space(3))) unsigned int*)(hstage + v * 16), 16, 0, 17);
            }
        }
        __syncthreads();   // both halves landed (per-thread vmcnt drained at barrier)

        // --- h-side preacts: conflict-free lane-linear LDS reads ---
        f32x4 ah = {0,0,0,0};
        if (t > 0) {
            #pragma unroll
            for (int kb = 0; kb < 32; kb++) {
                bf16x8 w = ld_bf8(whl + kb * 1024 + lane * 16);
                bf16x8 a = ld_bf8(hstage + kb * 1024 + lane * 16);
                ah = __builtin_amdgcn_mfma_f32_16x16x32_bf16(a, w, ah, 0, 0, 0);
            }
        }

        // --- exchange r-pre and both hcand parts via LDS ---
        if (g == 1) {
            f32x4 v;
            #pragma unroll
            for (int r = 0; r < 4; r++) v[r] = ah[r] + ax[r] + brv;
            Px[0 * 64 + lane] = v;
        } else if (g == 2) {
            f32x4 v, w;
            #pragma unroll
            for (int r = 0; r < 4; r++) { v[r] = ah[r] + bhhv; w[r] = ax[r] + bxhv; }
            Px[1 * 64 + lane] = v;
            Px[2 * 64 + lane] = w;
        }
        __syncthreads();

        // --- finalize by wave 0: gates -> new h -> T-repack -> ONE 8B coherent store/lane ---
        if (g == 0) {
            unsigned short* hdst = hs + (size_t)(t + 1) * BH;
            f32x4 pr = Px[0 * 64 + lane];
            f32x4 ph_ = Px[1 * 64 + lane];
            f32x4 px_ = Px[2 * 64 + lane];
            #pragma unroll
            for (int r = 0; r < 4; r++) {
                float z  = 1.f / (1.f + __expf(-(ah[r] + ax[r] + bzv)));
                float rr = 1.f / (1.f + __expf(-pr[r]));
                float hc = tanhf(px_[r] + rr * ph_[r]);
                hst[r] = (1.f - z) * hst[r] + z * hc;
                T[(hi * 4 + r) * 16 + lo] = f2bf(hst[r]);   // T[row16][col16]
            }
            asm volatile("s_waitcnt lgkmcnt(0)" ::: "memory");  // cross-lane T writes complete
            int row = lane >> 2, q = lane & 3;
            unsigned long long val = *(const unsigned long long*)(T + row * 16 + q * 4);
            st_u64c(hdst + (size_t)(rb * 16 + row) * HID + cb * 16 + q * 4, val);
            asm volatile("s_waitcnt vmcnt(0)" ::: "memory");    // h-store at the IF
        }
        if (tid == 0)
            __hip_atomic_store(flags + rb * 64 + cb, (unsigned int)(t + 1),
                               __ATOMIC_RELAXED, __HIP_MEMORY_SCOPE_AGENT);

        // --- x-prefetch for t+1 (L2-warm) overlaps flag propagation; then poll half A ---
        f32x4 nax = {0,0,0,0};
        if (t + 1 < SEQL) {
            const unsigned short* xp = xbf + ((size_t)(t + 1) * BATCH + rb * 16 + lo) * INF + hi * 8;
            #pragma unroll
            for (int kb = 0; kb < 16; kb++)
                nax = __builtin_amdgcn_mfma_f32_16x16x32_bf16(ld_bf8(xp + kb * 32), ld_bf8(wxp + kb * 32), nax, 0, 0, 0);
            unsigned int tgt = (unsigned int)(t + 1);
            while (!__all(__hip_atomic_load(flA, __ATOMIC_RELAXED, __HIP_MEMORY_SCOPE_AGENT) >= tgt))
                __builtin_amdgcn_s_sleep(1);
        }
        ax = nax;
    }
}

// ---------------- host ----------------
extern "C" void kernel_launch(void* const* d_in, const int* in_sizes, int n_in,
                              void* d_out, int out_size, void* d_ws, size_t ws_size,
                              hipStream_t stream) {
    const float* x   = (const float*)d_in[0];
    const float* Wxz = (const float*)d_in[1];
    const float* bxz = (const float*)d_in[2];
    const float* Whz = (const float*)d_in[3];
    const float* bhz = (const float*)d_in[4];
    const float* Wxr = (const float*)d_in[5];
    const float* bxr = (const float*)d_in[6];
    const float* Whr = (const float*)d_in[7];
    const float* bhr = (const float*)d_in[8];
    const float* Wxh = (const float*)d_in[9];
    const float* bxh = (const float*)d_in[10];
    const float* Whh = (const float*)d_in[11];
    const float* bhh = (const float*)d_in[12];
    const float* Why = (const float*)d_in[13];
    const float* bhy = (const float*)d_in[14];

    char* ws = (char*)d_ws;
    size_t off = 0;
    auto alloc = [&](size_t bytes) { char* p = ws + off; off += (bytes + 255) & ~(size_t)255; return p; };
    unsigned short* Whc   = (unsigned short*)alloc((size_t)3 * HID * HID * 2);
    unsigned short* Wxc   = (unsigned short*)alloc((size_t)3 * HID * INF * 2);
    unsigned short* Whyb  = (unsigned short*)alloc((size_t)OUTF * HID * 2);
    float*          bias2 = (float*)alloc((size_t)2 * HID * 4);
    unsigned short* hsbuf = (unsigned short*)alloc((size_t)(SEQL + 1) * BATCH * HID * 2);
    unsigned int*   flags = (unsigned int*)alloc(1024);
    unsigned short* x_bf  = (unsigned short*)d_out;  // dead until the final GEMM

    if (off > ws_size) {
        fail_sentinel<<<dim3(1), dim3(1), 0, stream>>>((float*)d_out);
        return;
    }

    auto cvt = [&](const float* s, unsigned short* d, size_t n) {
        cvt_f32_bf16<<<dim3((unsigned)((n / 4 + 255) / 256)), dim3(256), 0, stream>>>(s, d, (int)n);
    };
    cvt(x, x_bf, (size_t)SB * INF);
    cvt(Whz, Whc, (size_t)HID * HID);
    cvt(Whr, Whc + (size_t)HID * HID, (size_t)HID * HID);
    cvt(Whh, Whc + (size_t)2 * HID * HID, (size_t)HID * HID);
    cvt(Wxz, Wxc, (size_t)HID * INF);
    cvt(Wxr, Wxc + (size_t)HID * INF, (size_t)HID * INF);
    cvt(Wxh, Wxc + (size_t)2 * HID * INF, (size_t)HID * INF);
    cvt(Why, Whyb, (size_t)OUTF * HID);
    make_bias2<<<dim3(8), dim3(256), 0, stream>>>(bxz, bhz, bxr, bhr, bias2);
    (void)hipMemsetAsync(flags, 0, 1024, stream);   // reset per launch (graph-replay safe)

    gru_scan<<<dim3(256), dim3(192), 0, stream>>>(Whc, Wxc, x_bf, hsbuf, bias2, bxh, bhh, flags);

    gemm_nt_f32<<<dim3((SB / 128) * (OUTF / 128)), dim3(256), 0, stream>>>(
        hsbuf + (size_t)BATCH * HID, HID, Whyb, HID, bhy, (float*)d_out, OUTF, HID);
}

// Round 11
// 2920.968 us; speedup vs baseline: 1.2260x; 1.0652x over previous
//
#include <hip/hip_runtime.h>
#include <hip/hip_bf16.h>

// GRU: SEQ=512, B=64, I=512, H=1024, O=512
#define SEQL 512
#define BATCH 64
#define INF 512
#define HID 1024
#define OUTF 512
#define SB (SEQL*BATCH)
#define BH (BATCH*HID)

typedef __attribute__((ext_vector_type(8))) __bf16 bf16x8;
typedef __attribute__((ext_vector_type(4))) float f32x4;

__device__ inline bf16x8 ld_bf8(const void* p) { return *reinterpret_cast<const bf16x8*>(p); }
__device__ inline unsigned short f2bf(float f) { __bf16 b = (__bf16)f; return __builtin_bit_cast(unsigned short, b); }

// Coherent 8B store: relaxed agent-scope atomic -> write-through to IF, no cache maintenance.
__device__ inline void st_u64c(void* p, unsigned long long v) {
    __hip_atomic_store((unsigned long long*)p, v, __ATOMIC_RELAXED, __HIP_MEMORY_SCOPE_AGENT);
}

// ---------------- prep kernels ----------------
__global__ void cvt_f32_bf16(const float* __restrict__ src, unsigned short* __restrict__ dst, int n) {
    int i = (blockIdx.x * blockDim.x + threadIdx.x) * 4;
    if (i < n) {
        float4 v = *reinterpret_cast<const float4*>(src + i);
        ushort4 o = make_ushort4(f2bf(v.x), f2bf(v.y), f2bf(v.z), f2bf(v.w));
        *reinterpret_cast<ushort4*>(dst + i) = o;
    }
}

__global__ void make_bias2(const float* bxz, const float* bhz, const float* bxr,
                           const float* bhr, float* bias2) {
    int i = blockIdx.x * blockDim.x + threadIdx.x;
    if (i < HID) bias2[i] = bxz[i] + bhz[i];
    else if (i < 2*HID) bias2[i] = bxr[i-HID] + bhr[i-HID];
}

__global__ void fail_sentinel(float* o) { o[0] = 1e9f; }

// ---------------- tiled NT GEMM (unchanged, validated) ----------------
__global__ __launch_bounds__(256, 2) void gemm_nt_f32(
        const unsigned short* __restrict__ A, int lda,
        const unsigned short* __restrict__ Bw, int ldb,
        const float* __restrict__ bias,
        float* __restrict__ Cf, int N, int K) {
    __shared__ __align__(16) char lds[32768];
    const int tid = threadIdx.x;
    const int ntn = N >> 7;
    const int bm = blockIdx.x / ntn, bn = blockIdx.x % ntn;
    const int rowbase = bm << 7, colbase = bn << 7;
    const int wave = tid >> 6, lane = tid & 63, lo = lane & 15, hi = lane >> 4;
    const int vm = wave >> 1, vn = wave & 1;

    auto stage = [&](int abase, int k0) {
        #pragma unroll
        for (int i = 0; i < 2; i++) {
            int linear = i * 256 + tid;
            int r = linear >> 2, s = linear & 3;
            int c = (s - (r >> 1)) & 3;
            const unsigned short* ga = A + (size_t)(rowbase + r) * lda + k0 + c * 8;
            const unsigned short* gb = Bw + (size_t)(colbase + r) * ldb + k0 + c * 8;
            __builtin_amdgcn_global_load_lds(
                (const __attribute__((address_space(1))) unsigned int*)ga,
                (__attribute__((address_space(3))) unsigned int*)(lds + abase + linear * 16), 16, 0, 0);
            __builtin_amdgcn_global_load_lds(
                (const __attribute__((address_space(1))) unsigned int*)gb,
                (__attribute__((address_space(3))) unsigned int*)(lds + 16384 + abase + linear * 16), 16, 0, 0);
        }
    };

    f32x4 acc[4][4] = {};
    const int nk = K >> 5;
    stage(0, 0);
    for (int kt = 0; kt < nk; kt++) {
        __syncthreads();
        if (kt + 1 < nk) stage(((kt + 1) & 1) * 8192, (kt + 1) << 5);
        const char* cA = lds + (kt & 1) * 8192;
        const char* cB = lds + 16384 + (kt & 1) * 8192;
        bf16x8 af[4], bfr[4];
        #pragma unroll
        for (int m = 0; m < 4; m++) {
            int r = vm * 64 + m * 16 + lo;
            af[m] = ld_bf8(cA + r * 64 + 16 * ((hi + (r >> 1)) & 3));
        }
        #pragma unroll
        for (int n = 0; n < 4; n++) {
            int r = vn * 64 + n * 16 + lo;
            bfr[n] = ld_bf8(cB + r * 64 + 16 * ((hi + (r >> 1)) & 3));
        }
        #pragma unroll
        for (int m = 0; m < 4; m++)
            #pragma unroll
            for (int n = 0; n < 4; n++)
                acc[m][n] = __builtin_amdgcn_mfma_f32_16x16x32_bf16(af[m], bfr[n], acc[m][n], 0, 0, 0);
        __syncthreads();
    }

    #pragma unroll
    for (int n = 0; n < 4; n++) {
        int col = colbase + vn * 64 + n * 16 + lo;
        float bv = bias[col];
        #pragma unroll
        for (int m = 0; m < 4; m++)
            #pragma unroll
            for (int r = 0; r < 4; r++) {
                int row = rowbase + vm * 64 + m * 16 + hi * 4 + r;
                Cf[(size_t)row * N + col] = acc[m][n][r] + bv;
            }
    }
}

// ---------------- persistent GRU scan v7: L2-shared cached staging ----------------
// 256 WGs x 192 threads; rb = wid>>6 in 0..3 (16 batch rows, 4 independent scan groups),
// cb = wid&63 (16 h-cols); wave g = gate {z,r,hcand}.
// LDS: [0,96K) wh; [96K,128K) h tile (fragment-major, r8-validated ~0 conflicts);
//      [128K,131K) Px; [131K,131.5K) T repack.
// ROUND-10 POST-MORTEM: aux=17 bypass staging sent 64 WGs x 32KB of identical h data as
// ~524K tiny transactions to the IF every step. NOW: plain CACHED staging (aux=0).
// Coherence argument: each hs+t*BH address is bypass-WRITTEN once (to IF) then cache-READ
// once, only after the producer flag. The reader's XCD never touched that line during this
// launch -> guaranteed L2 miss -> served by the IF, which holds fresh data (flag ordering).
// First WG per XCD per line misses to IF; the other ~7 same-group WGs HIT L2 (8x less IF
// traffic). Stale lines can only predate the launch (graph replay) -> ONE buffer_inv per WG
// at kernel start kills them.
// Sync (validated r8/r10): split-half flag pipeline; wave0 repack -> one 8B coherent
// store/lane -> vmcnt(0) -> per-WG flag store (no RMW); x-prefetch between flag and poll-A.
__global__ __launch_bounds__(192, 1) void gru_scan(
        const unsigned short* __restrict__ Whc,   // [3][H][H]
        const unsigned short* __restrict__ Wxc,   // [3][H][I]
        const unsigned short* __restrict__ xbf,   // [S*B][I]
        unsigned short* __restrict__ hs,          // [S+1][B][H]
        const float* __restrict__ bias2,          // [2H]
        const float* __restrict__ bxh,
        const float* __restrict__ bhh,
        unsigned int* flags) {                    // [4][64] per-WG step flags
    __shared__ __align__(16) char lds[134656];
    const int tid = threadIdx.x;
    const int wid = blockIdx.x;
    const int rb = wid >> 6;          // 0..3
    const int cb = wid & 63;
    const int g = tid / 64;
    const int lane = tid & 63, lo = lane & 15, hi = lane >> 4;
    const int col = cb * 16 + lo;
    char* whl = lds + g * 32768;                       // this wave's 32 wh frags
    char* hstage = lds + 98304;                        // 32 KB fragment-major h tile
    f32x4* Px = (f32x4*)(lds + 131072);                // 3 KB exchange
    unsigned short* T = (unsigned short*)(lds + 134144); // 512 B store-repack

    // ---- stage wh slices into LDS (once) ----
    {
        const unsigned short* ph = Whc + ((size_t)g * HID + col) * HID + hi * 8;
        #pragma unroll
        for (int kb = 0; kb < 32; kb++)
            __builtin_amdgcn_global_load_lds(
                (const __attribute__((address_space(1))) unsigned int*)(ph + kb * 32),
                (__attribute__((address_space(3))) unsigned int*)(whl + kb * 1024 + lane * 16), 16, 0, 0);
    }
    __syncthreads();
    // Kill any pre-launch (previous graph replay) L2 lines of hsbuf before the first h read.
    // Weights already live in LDS; x/W re-fetches after this are L2-warm within a few steps.
    asm volatile("buffer_inv sc0 sc1" ::: "memory");

    const float bzv  = bias2[col];
    const float brv  = bias2[HID + col];
    const float bxhv = bxh[col];
    const float bhhv = bhh[col];
    float hst[4] = {0.f, 0.f, 0.f, 0.f};   // fp32 state: row = rb*16 + hi*4 + r, col
    const unsigned short* wxp = Wxc + ((size_t)g * HID + col) * INF + hi * 8;
    const unsigned int* flA = flags + rb * 64 + (lane & 31);        // half-A producers
    const unsigned int* flB = flags + rb * 64 + 32 + (lane & 31);   // half-B producers

    // x-side preacts for t=0
    f32x4 ax = {0,0,0,0};
    {
        const unsigned short* xp = xbf + ((size_t)(rb * 16 + lo)) * INF + hi * 8;
        #pragma unroll
        for (int kb = 0; kb < 16; kb++)
            ax = __builtin_amdgcn_mfma_f32_16x16x32_bf16(ld_bf8(xp + kb * 32), ld_bf8(wxp + kb * 32), ax, 0, 0, 0);
    }

    for (int t = 0; t < SEQL; t++) {
        // --- stage h[t]: half A, CACHED (poll-A happened at end of previous iteration) ---
        if (t > 0) {
            const unsigned short* hsrc = hs + (size_t)t * BH + (size_t)(rb * 16) * HID;
            #pragma unroll
            for (int it = 0; it < 6; it++) {
                int v = it * 192 + tid;
                if (v < 1024)
                    __builtin_amdgcn_global_load_lds(
                        (const __attribute__((address_space(1))) unsigned int*)(hsrc + (size_t)(v & 15) * HID + (v >> 4) * 8),
                        (__attribute__((address_space(3))) unsigned int*)(hstage + v * 16), 16, 0, 0 /*cached*/);
            }
            // --- poll half-B producers; A-loads complete under this RTT ---
            {
                unsigned int tgt = (unsigned int)t;
                while (!__all(__hip_atomic_load(flB, __ATOMIC_RELAXED, __HIP_MEMORY_SCOPE_AGENT) >= tgt))
                    __builtin_amdgcn_s_sleep(1);
            }
            // --- stage half B, CACHED ---
            #pragma unroll
            for (int it = 0; it < 6; it++) {
                int v = 1024 + it * 192 + tid;
                if (v < 2048)
                    __builtin_amdgcn_global_load_lds(
                        (const __attribute__((address_space(1))) unsigned int*)(hsrc + (size_t)(v & 15) * HID + (v >> 4) * 8),
                        (__attribute__((address_space(3))) unsigned int*)(hstage + v * 16), 16, 0, 0);
            }
        }
        __syncthreads();   // both halves landed (per-thread vmcnt drained at barrier)

        // --- h-side preacts: conflict-free lane-linear LDS reads ---
        f32x4 ah = {0,0,0,0};
        if (t > 0) {
            #pragma unroll
            for (int kb = 0; kb < 32; kb++) {
                bf16x8 w = ld_bf8(whl + kb * 1024 + lane * 16);
                bf16x8 a = ld_bf8(hstage + kb * 1024 + lane * 16);
                ah = __builtin_amdgcn_mfma_f32_16x16x32_bf16(a, w, ah, 0, 0, 0);
            }
        }

        // --- exchange r-pre and both hcand parts via LDS ---
        if (g == 1) {
            f32x4 v;
            #pragma unroll
            for (int r = 0; r < 4; r++) v[r] = ah[r] + ax[r] + brv;
            Px[0 * 64 + lane] = v;
        } else if (g == 2) {
            f32x4 v, w;
            #pragma unroll
            for (int r = 0; r < 4; r++) { v[r] = ah[r] + bhhv; w[r] = ax[r] + bxhv; }
            Px[1 * 64 + lane] = v;
            Px[2 * 64 + lane] = w;
        }
        __syncthreads();

        // --- finalize by wave 0: gates -> new h -> T-repack -> ONE 8B coherent store/lane ---
        if (g == 0) {
            unsigned short* hdst = hs + (size_t)(t + 1) * BH;
            f32x4 pr = Px[0 * 64 + lane];
            f32x4 ph_ = Px[1 * 64 + lane];
            f32x4 px_ = Px[2 * 64 + lane];
            #pragma unroll
            for (int r = 0; r < 4; r++) {
                float z  = 1.f / (1.f + __expf(-(ah[r] + ax[r] + bzv)));
                float rr = 1.f / (1.f + __expf(-pr[r]));
                float hc = tanhf(px_[r] + rr * ph_[r]);
                hst[r] = (1.f - z) * hst[r] + z * hc;
                T[(hi * 4 + r) * 16 + lo] = f2bf(hst[r]);   // T[row16][col16]
            }
            asm volatile("s_waitcnt lgkmcnt(0)" ::: "memory");  // cross-lane T writes complete
            int row = lane >> 2, q = lane & 3;
            unsigned long long val = *(const unsigned long long*)(T + row * 16 + q * 4);
            st_u64c(hdst + (size_t)(rb * 16 + row) * HID + cb * 16 + q * 4, val);
            asm volatile("s_waitcnt vmcnt(0)" ::: "memory");    // h-store at the IF
        }
        if (tid == 0)
            __hip_atomic_store(flags + rb * 64 + cb, (unsigned int)(t + 1),
                               __ATOMIC_RELAXED, __HIP_MEMORY_SCOPE_AGENT);

        // --- x-prefetch for t+1 (L2-warm) overlaps flag propagation; then poll half A ---
        f32x4 nax = {0,0,0,0};
        if (t + 1 < SEQL) {
            const unsigned short* xp = xbf + ((size_t)(t + 1) * BATCH + rb * 16 + lo) * INF + hi * 8;
            #pragma unroll
            for (int kb = 0; kb < 16; kb++)
                nax = __builtin_amdgcn_mfma_f32_16x16x32_bf16(ld_bf8(xp + kb * 32), ld_bf8(wxp + kb * 32), nax, 0, 0, 0);
            unsigned int tgt = (unsigned int)(t + 1);
            while (!__all(__hip_atomic_load(flA, __ATOMIC_RELAXED, __HIP_MEMORY_SCOPE_AGENT) >= tgt))
                __builtin_amdgcn_s_sleep(1);
        }
        ax = nax;
    }
}

// ---------------- host ----------------
extern "C" void kernel_launch(void* const* d_in, const int* in_sizes, int n_in,
                              void* d_out, int out_size, void* d_ws, size_t ws_size,
                              hipStream_t stream) {
    const float* x   = (const float*)d_in[0];
    const float* Wxz = (const float*)d_in[1];
    const float* bxz = (const float*)d_in[2];
    const float* Whz = (const float*)d_in[3];
    const float* bhz = (const float*)d_in[4];
    const float* Wxr = (const float*)d_in[5];
    const float* bxr = (const float*)d_in[6];
    const float* Whr = (const float*)d_in[7];
    const float* bhr = (const float*)d_in[8];
    const float* Wxh = (const float*)d_in[9];
    const float* bxh = (const float*)d_in[10];
    const float* Whh = (const float*)d_in[11];
    const float* bhh = (const float*)d_in[12];
    const float* Why = (const float*)d_in[13];
    const float* bhy = (const float*)d_in[14];

    char* ws = (char*)d_ws;
    size_t off = 0;
    auto alloc = [&](size_t bytes) { char* p = ws + off; off += (bytes + 255) & ~(size_t)255; return p; };
    unsigned short* Whc   = (unsigned short*)alloc((size_t)3 * HID * HID * 2);
    unsigned short* Wxc   = (unsigned short*)alloc((size_t)3 * HID * INF * 2);
    unsigned short* Whyb  = (unsigned short*)alloc((size_t)OUTF * HID * 2);
    float*          bias2 = (float*)alloc((size_t)2 * HID * 4);
    unsigned short* hsbuf = (unsigned short*)alloc((size_t)(SEQL + 1) * BATCH * HID * 2);
    unsigned int*   flags = (unsigned int*)alloc(1024);
    unsigned short* x_bf  = (unsigned short*)d_out;  // dead until the final GEMM

    if (off > ws_size) {
        fail_sentinel<<<dim3(1), dim3(1), 0, stream>>>((float*)d_out);
        return;
    }

    auto cvt = [&](const float* s, unsigned short* d, size_t n) {
        cvt_f32_bf16<<<dim3((unsigned)((n / 4 + 255) / 256)), dim3(256), 0, stream>>>(s, d, (int)n);
    };
    cvt(x, x_bf, (size_t)SB * INF);
    cvt(Whz, Whc, (size_t)HID * HID);
    cvt(Whr, Whc + (size_t)HID * HID, (size_t)HID * HID);
    cvt(Whh, Whc + (size_t)2 * HID * HID, (size_t)HID * HID);
    cvt(Wxz, Wxc, (size_t)HID * INF);
    cvt(Wxr, Wxc + (size_t)HID * INF, (size_t)HID * INF);
    cvt(Wxh, Wxc + (size_t)2 * HID * INF, (size_t)HID * INF);
    cvt(Why, Whyb, (size_t)OUTF * HID);
    make_bias2<<<dim3(8), dim3(256), 0, stream>>>(bxz, bhz, bxr, bhr, bias2);
    (void)hipMemsetAsync(flags, 0, 1024, stream);   // reset per launch (graph-replay safe)

    gru_scan<<<dim3(256), dim3(192), 0, stream>>>(Whc, Wxc, x_bf, hsbuf, bias2, bxh, bhh, flags);

    gemm_nt_f32<<<dim3((SB / 128) * (OUTF / 128)), dim3(256), 0, stream>>>(
        hsbuf + (size_t)BATCH * HID, HID, Whyb, HID, bhy, (float*)d_out, OUTF, HID);
}